// Round 1
// 144.746 us; speedup vs baseline: 1.0972x; 1.0972x over previous
//
#include <hip/hip_runtime.h>

typedef unsigned short u16;
typedef unsigned int   u32;

#define NB 4
#define NT 4096
#define NC 512
#define NH 64
#define ATT_SCALE 0.044194173824159216f
#define LOG2E     1.4426950408889634f
#define QSCALE    (ATT_SCALE * LOG2E)     // log2e folded: exp2 domain everywhere
#define NEG_BIG   -30000.0f
#define ITEMS_PB  1088     // base 4-tile items per batch (sum 8m, m=1..16)
#define ITEMS2_PB 2176     // strip-split items per batch (2 strips per base item)

typedef __attribute__((ext_vector_type(8))) _Float16 half8;
typedef __attribute__((ext_vector_type(4))) _Float16 half4;
typedef __attribute__((ext_vector_type(4))) float    floatx4;

// Fragment-layout addressing: all MFMA operands live in 1KB blocks of 512
// halves; element (id, q4, j) at id*32 + q4*8 + j. A wave load for one
// operand is lane-offset id*32+quad*8 (halves) = one contiguous 1KB burst.

// ---------------------------------------------------------------------------
// Kernel 0: W (fp32) -> Wh' fragment layout [w][ks16][nt4]{1KB blocks};
// w: 0=q(QSCALE folded), 1=k, 2=v.
// ---------------------------------------------------------------------------
__global__ __launch_bounds__(256) void wconv(
    const float* __restrict__ Wk, const float* __restrict__ Wq,
    const float* __restrict__ Wv, _Float16* __restrict__ Wh)
{
    const int gid = blockIdx.x * 256 + threadIdx.x;   // 24576 float4s
    const int w = gid >> 13;
    const int i = gid & 8191;                         // float4 within 64x512
    const int h = i >> 7, c = (i & 127) * 4;
    const float* src = (w == 0) ? Wq : (w == 1) ? Wk : Wv;
    const float sc = (w == 0) ? QSCALE : 1.0f;
    float4 f = *(const float4*)&src[h * NC + c];
    half4 o = {(_Float16)(f.x * sc), (_Float16)(f.y * sc),
               (_Float16)(f.z * sc), (_Float16)(f.w * sc)};
    const int blk = ((w * 16 + (c >> 5)) * 4 + (h >> 4));
    *(half4*)&Wh[(size_t)blk * 512 + (h & 15) * 32 + ((c >> 3) & 3) * 8 + (c & 7)] = o;
}

// ---------------------------------------------------------------------------
// Kernel 1: q/k/v projection GEMM, 4-way k-split. Block = 256 thr = 4 waves
// (kh 0-3); block does 16 rows x 512 k. Each wave: 4 ks-steps x 12 MFMA over
// its 128 k-cols; waves 1-3 park partials in 36.9KB LDS, wave 0 reduces and
// writes Q'/K'/V' fragment layouts. Grid 1024 blocks = 4096 waves (2x the
// previous 2048 -> better latency hiding).
// Q': [b][q16 256][hop2]{1KB}   K': [b][kt64][t4][hop2]{1KB}
// V': [b][kt64][th4][kop2]{1KB}
// ---------------------------------------------------------------------------
__global__ __launch_bounds__(256) void qkv_mfma(
    const float* __restrict__ x, const _Float16* __restrict__ Wh,
    _Float16* __restrict__ Qf, _Float16* __restrict__ Kf,
    _Float16* __restrict__ Vf)
{
    __shared__ __align__(16) floatx4 red[3][12][64];  // 36.9 KB

    const int tid  = threadIdx.x;
    const int wv   = tid >> 6;                        // kh 0..3
    const int lane = tid & 63;
    const int quad = lane >> 4;
    const int id   = lane & 15;
    const int rowbase = blockIdx.x * 16;

    floatx4 acc[3][4] = {};
    const float* xp = x + (size_t)(rowbase + id) * NC + wv * 128;
    const int loff = id * 32 + quad * 8;              // frag lane offset (halves)

#pragma unroll
    for (int ks = 0; ks < 4; ++ks) {
        float4 f0 = *(const float4*)&xp[ks * 32 + quad * 8];
        float4 f1 = *(const float4*)&xp[ks * 32 + quad * 8 + 4];
        half8 a;
        a[0] = (_Float16)f0.x; a[1] = (_Float16)f0.y;
        a[2] = (_Float16)f0.z; a[3] = (_Float16)f0.w;
        a[4] = (_Float16)f1.x; a[5] = (_Float16)f1.y;
        a[6] = (_Float16)f1.z; a[7] = (_Float16)f1.w;
        const int ksg = wv * 4 + ks;
#pragma unroll
        for (int w = 0; w < 3; ++w)
#pragma unroll
            for (int nt = 0; nt < 4; ++nt) {
                half8 bf = *(const half8*)&Wh[(size_t)((w * 16 + ksg) * 4 + nt) * 512 + loff];
                acc[w][nt] = __builtin_amdgcn_mfma_f32_16x16x32_f16(a, bf, acc[w][nt], 0, 0, 0);
            }
    }

    if (wv) {
#pragma unroll
        for (int w = 0; w < 3; ++w)
#pragma unroll
            for (int nt = 0; nt < 4; ++nt)
                red[wv - 1][w * 4 + nt][lane] = acc[w][nt];
    }
    __syncthreads();
    if (wv) return;

#pragma unroll
    for (int w = 0; w < 3; ++w)
#pragma unroll
        for (int nt = 0; nt < 4; ++nt) {
            floatx4 a0 = red[0][w * 4 + nt][lane];
            floatx4 a1 = red[1][w * 4 + nt][lane];
            floatx4 a2 = red[2][w * 4 + nt][lane];
            acc[w][nt] += a0 + a1 + a2;
        }

    // epilogue: C-frag (row=quad*4+r, h=nt*16+id) -> fragment layouts
    const int b  = rowbase >> 12, L = rowbase & 4095;
    const int q16 = L >> 4, kt = L >> 6, tt = (L >> 4) & 3;
    const int kop = ((rowbase & 63) + quad * 4) >> 5;
    const int q4k = ((((rowbase & 63) + quad * 4) >> 3) & 3);
#pragma unroll
    for (int nt = 0; nt < 4; ++nt) {
        const int hop = nt >> 1;
        const int q4h = (nt * 2 + (id >> 3)) & 3;
        const int j   = id & 7;
        const size_t qa = (size_t)((b * 256 + q16) * 2 + hop) * 512 + q4h * 8 + j;
        const size_t ka = (size_t)(((b * 64 + kt) * 4 + tt) * 2 + hop) * 512 + q4h * 8 + j;
#pragma unroll
        for (int r = 0; r < 4; ++r) {
            Qf[qa + (quad * 4 + r) * 32] = (_Float16)acc[0][nt][r];
            Kf[ka + (quad * 4 + r) * 32] = (_Float16)acc[1][nt][r];
        }
        half4 vh = {(_Float16)acc[2][nt][0], (_Float16)acc[2][nt][1],
                    (_Float16)acc[2][nt][2], (_Float16)acc[2][nt][3]};
        const size_t va = (size_t)(((b * 64 + kt) * 4 + nt) * 2 + kop) * 512
                        + id * 32 + q4k * 8 + (quad & 1) * 4;
        *(half4*)&Vf[va] = vh;
    }
}

// ---------------------------------------------------------------------------
// Kernel 2: attention partials — strip-split: 1 wave = 16 q-rows (one strip)
// x <=4 k-tiles. item2 = base_item*2 + strip; 2176 items/batch, 4 waves per
// 256-thr block -> grid 544x4 = 2176 blocks (4x the old 544). Per-wave regs
// ~halved vs the 2-strip version -> target 6 waves/SIMD. Transposed flash
// (S^T = K Q^T, O^T = V^T P^T), per-lane softmax in exp2 domain, P via
// wave-private LDS; epilogue bounces O through LDS so each global store
// covers a full contiguous 1KB (kills write-allocate RMW on Opart).
// ---------------------------------------------------------------------------
__global__ __launch_bounds__(256, 6) void attn_part(
    const _Float16* __restrict__ Qf, const _Float16* __restrict__ Kf,
    const _Float16* __restrict__ Vf, _Float16* __restrict__ Opart,
    float2* __restrict__ MLpart)
{
    constexpr int KP = 72;
    __shared__ __align__(16) _Float16 Ps[4][16 * KP];   // 9.2 KB

    const int tid  = threadIdx.x;
    const int wv   = tid >> 6;
    const int lane = tid & 63;
    const int quad = lane >> 4;
    const int id   = lane & 15;
    const int item2 = blockIdx.x * 4 + wv;     // [0, 2176)
    const int item  = item2 >> 1;              // base 4-tile item
    const int st    = item2 & 1;               // strip (16-row half)
    const int b     = blockIdx.y;
    const int loff  = id * 32 + quad * 8;      // frag lane offset (halves)

    // decode base item -> (qs, seg): group m starts at 4m(m-1), has 8m items
    int m = (int)((1.0f + __builtin_sqrtf((float)item + 1.0f)) * 0.5f);
    while (4 * m * (m + 1) <= item) ++m;
    while (m > 1 && 4 * m * (m - 1) > item) --m;
    const int rem  = item - 4 * m * (m - 1);
    const int qs   = 8 * (m - 1) + rem / m;
    const int seg  = rem - (rem / m) * m;
    const int ntiles = (qs >> 1) + 1;
    const int t0 = seg * ntiles / m;
    const int t1 = (seg + 1) * ntiles / m;

    // Q fragments for this strip (pre-scaled by ATT_SCALE*log2e): 2 h-halves
    const size_t qa = (size_t)((b * 256 + qs * 2 + st) * 2) * 512 + loff;
    half8 qb0 = *(const half8*)&Qf[qa];
    half8 qb1 = *(const half8*)&Qf[qa + 512];

    floatx4 o[4] = {};
    float m_i = NEG_BIG, l_i = 0.f;

    for (int kt = t0; kt < t1; ++kt) {
        const size_t tb = (size_t)((b * 64 + kt) * 4) * 2 * 512;  // tile base (halves)

        // S^T: A = K frags (1KB loads), B = Q frags
        floatx4 s4[4] = {};
#pragma unroll
        for (int t = 0; t < 4; ++t) {
            half8 ka0 = *(const half8*)&Kf[tb + (size_t)t * 1024 + loff];
            half8 ka1 = *(const half8*)&Kf[tb + (size_t)t * 1024 + 512 + loff];
            s4[t] = __builtin_amdgcn_mfma_f32_16x16x32_f16(ka0, qb0, s4[t], 0, 0, 0);
            s4[t] = __builtin_amdgcn_mfma_f32_16x16x32_f16(ka1, qb1, s4[t], 0, 0, 0);
        }

        // hoist V t=0 to overlap softmax latency
        half8 va00 = *(const half8*)&Vf[tb + loff];
        half8 va01 = *(const half8*)&Vf[tb + 512 + loff];

        if (kt == ntiles - 1) {                // diagonal tile: causal mask
            const int kb = kt * 64;
            const int qrow = qs * 32 + st * 16 + id;
#pragma unroll
            for (int t = 0; t < 4; ++t)
#pragma unroll
                for (int r = 0; r < 4; ++r)
                    if (kb + 16 * t + quad * 4 + r > qrow)
                        s4[t][r] = NEG_BIG;
        }

        // online softmax (exp2 domain): in-lane(16) + 2 shuffles
        float mx = s4[0][0];
#pragma unroll
        for (int t = 0; t < 4; ++t)
#pragma unroll
            for (int r = 0; r < 4; ++r) mx = fmaxf(mx, s4[t][r]);
        mx = fmaxf(mx, __shfl_xor(mx, 16));
        mx = fmaxf(mx, __shfl_xor(mx, 32));
        const float mnew  = fmaxf(m_i, mx);
        const float alpha = exp2f(m_i - mnew);
        m_i = mnew;
        float psum = 0.f;
#pragma unroll
        for (int t = 0; t < 4; ++t)
#pragma unroll
            for (int r = 0; r < 4; ++r) {
                float p = exp2f(s4[t][r] - mnew);
                s4[t][r] = p;
                psum += p;
            }
        psum += __shfl_xor(psum, 16);
        psum += __shfl_xor(psum, 32);
        l_i = l_i * alpha + psum;

#pragma unroll
        for (int t = 0; t < 4; ++t) {
            half4 ph = {(_Float16)s4[t][0], (_Float16)s4[t][1],
                        (_Float16)s4[t][2], (_Float16)s4[t][3]};
            *(half4*)&Ps[wv][id * KP + 16 * t + quad * 4] = ph;
        }
#pragma unroll
        for (int t = 0; t < 4; ++t)
#pragma unroll
            for (int r = 0; r < 4; ++r) o[t][r] *= alpha;

        // wave-private LDS round trip (lgkmcnt orders write->read)
        half8 pb0 = *(const half8*)&Ps[wv][id * KP + quad * 8];
        half8 pb1 = *(const half8*)&Ps[wv][id * KP + 32 + quad * 8];

        o[0] = __builtin_amdgcn_mfma_f32_16x16x32_f16(va00, pb0, o[0], 0, 0, 0);
        o[0] = __builtin_amdgcn_mfma_f32_16x16x32_f16(va01, pb1, o[0], 0, 0, 0);
#pragma unroll
        for (int t = 1; t < 4; ++t) {
            half8 v0 = *(const half8*)&Vf[tb + (size_t)t * 1024 + loff];
            half8 v1 = *(const half8*)&Vf[tb + (size_t)t * 1024 + 512 + loff];
            o[t] = __builtin_amdgcn_mfma_f32_16x16x32_f16(v0, pb0, o[t], 0, 0, 0);
            o[t] = __builtin_amdgcn_mfma_f32_16x16x32_f16(v1, pb1, o[t], 0, 0, 0);
        }
    }

    // epilogue: normalized O-hat (fp16) via LDS bounce -> full-line stores
    const int p = b * ITEMS2_PB + item2;
    const float rl = 1.f / l_i;
#pragma unroll
    for (int t = 0; t < 4; ++t) {
        half4 oh = {(_Float16)(o[t][0] * rl), (_Float16)(o[t][1] * rl),
                    (_Float16)(o[t][2] * rl), (_Float16)(o[t][3] * rl)};
        *(half4*)&Ps[wv][id * KP + 16 * t + quad * 4] = oh;   // row id, col h
    }
    // lane l stores 16B at byte offset l*16 of the item's 2KB region:
    // two instructions each covering a contiguous 1KB -> no RMW fill
    const int rr = lane >> 3, rc = (lane & 7) * 8;
    half8 u0 = *(const half8*)&Ps[wv][rr * KP + rc];
    half8 u1 = *(const half8*)&Ps[wv][(8 + rr) * KP + rc];
    _Float16* ob = &Opart[(size_t)(p * 16) * NH];
    *(half8*)&ob[rr * NH + rc] = u0;
    *(half8*)&ob[(8 + rr) * NH + rc] = u1;

    if (quad == 0)
        MLpart[p * 16 + id] = make_float2(m_i, l_i);
}

// ---------------------------------------------------------------------------
// Kernel 3: combine. Block per (qs, b): 32 rows x 8 col-chunks. The 8 lanes
// of a row cooperate: each owns <=2 partials (no runtime-indexed arrays ->
// no scratch), M and W via 8-lane shfl_xor reduce, per-partial weights
// fetched by __shfl, Opart loads issued 4-deep with clamped addresses.
// ---------------------------------------------------------------------------
__global__ __launch_bounds__(256) void attn_combine(
    const _Float16* __restrict__ Opart, const float2* __restrict__ MLpart,
    float* __restrict__ out)
{
    const int qs = blockIdx.x, b = blockIdx.y;
    const int tid = threadIdx.x;
    const int row = tid >> 3;          // 0..31
    const int hc  = tid & 7;
    const int lid = tid & 63;
    const int sst = row >> 4, r16 = row & 15;
    const int m = (qs >> 3) + 1;       // partials per row (<=16)
    const int base0 = 4 * m * (m - 1) + (qs - 8 * (m - 1)) * m;

    auto gidx = [&](int k) -> size_t {
        return (size_t)(b * ITEMS2_PB + (base0 + k) * 2 + sst) * 16 + r16;
    };

    // ownership: lane hc owns partials {hc, hc+8}
    float2 ml0 = make_float2(NEG_BIG, 0.f), ml1 = make_float2(NEG_BIG, 0.f);
    if (hc < m)     ml0 = MLpart[gidx(hc)];
    if (hc + 8 < m) ml1 = MLpart[gidx(hc + 8)];
    float M = fmaxf(ml0.x, ml1.x);
    M = fmaxf(M, __shfl_xor(M, 1));
    M = fmaxf(M, __shfl_xor(M, 2));
    M = fmaxf(M, __shfl_xor(M, 4));
    const float w0 = ml0.y * exp2f(ml0.x - M);
    const float w1 = ml1.y * exp2f(ml1.x - M);
    float W = w0 + w1;
    W += __shfl_xor(W, 1);
    W += __shfl_xor(W, 2);
    W += __shfl_xor(W, 4);

    float acc[8] = {};
    for (int k0 = 0; k0 < m; k0 += 4) {
        const int c0 = k0,     c1 = (k0 + 1 < m) ? k0 + 1 : m - 1;
        const int c2 = (k0 + 2 < m) ? k0 + 2 : m - 1;
        const int c3 = (k0 + 3 < m) ? k0 + 3 : m - 1;
        half8 o0 = *(const half8*)&Opart[gidx(c0) * NH + hc * 8];
        half8 o1 = *(const half8*)&Opart[gidx(c1) * NH + hc * 8];
        half8 o2 = *(const half8*)&Opart[gidx(c2) * NH + hc * 8];
        half8 o3 = *(const half8*)&Opart[gidx(c3) * NH + hc * 8];
#pragma unroll
        for (int i = 0; i < 4; ++i) {
            const int k = k0 + i;
            const float wsrc = (k < 8) ? w0 : w1;
            float ws = __shfl(wsrc, (lid & 56) | (k & 7));
            if (k >= m) ws = 0.f;
            const half8 oh = (i == 0) ? o0 : (i == 1) ? o1 : (i == 2) ? o2 : o3;
#pragma unroll
            for (int j = 0; j < 8; ++j) acc[j] += ws * (float)oh[j];
        }
    }
    const float rl = 1.f / W;
    float* dst = out + (size_t)(b * NT + qs * 32 + row) * NH + hc * 8;
#pragma unroll
    for (int j = 0; j < 8; ++j) dst[j] = acc[j] * rl;
}

extern "C" void kernel_launch(void* const* d_in, const int* in_sizes, int n_in,
                              void* d_out, int out_size, void* d_ws, size_t ws_size,
                              hipStream_t stream) {
    const float* x  = (const float*)d_in[0];
    const float* Wk = (const float*)d_in[1];
    const float* Wq = (const float*)d_in[2];
    const float* Wv = (const float*)d_in[3];

    // ws layout (25.43 MB): Qf/Kf/Vf 3x2MB | Wh 192KB | ML 1.06MB | Opart 17MB
    char* wsb = (char*)d_ws;
    _Float16* Qf    = (_Float16*)wsb;
    _Float16* Kf    = Qf + 1048576;
    _Float16* Vf    = Kf + 1048576;
    _Float16* Wh    = Vf + 1048576;
    float2*   MLpart= (float2*)(wsb + 6488064);
    _Float16* Opart = (_Float16*)(wsb + 7602176);

    wconv<<<96, 256, 0, stream>>>(Wk, Wq, Wv, Wh);
    qkv_mfma<<<1024, 256, 0, stream>>>(x, Wh, Qf, Kf, Vf);
    attn_part<<<dim3(ITEMS2_PB / 4, NB), 256, 0, stream>>>(Qf, Kf, Vf, Opart, MLpart);
    attn_combine<<<dim3(128, NB), 256, 0, stream>>>(Opart, MLpart, (float*)d_out);
}